// Round 7
// baseline (66.739 us; speedup 1.0000x reference)
//
#include <hip/hip_runtime.h>

// SIR RK4, B=65536, 200 points, out (B,200,3) f32 = 157.3 MB.
// Round 7: de-phase co-resident waves. Same structure as R3 (64 systems per
// single-wave block, barrier-free, LDS transpose, coalesced float4 flush),
// but the chunk schedule is staggered by block: w=(blockIdx>>8)&3 picks the
// first-chunk size {12,24,36,40} pts, then 4x40, then remainder {28,16,4,0}.
// Co-resident blocks {i,i+256,i+512,i+768} get w={0,1,2,3} -> flush bursts
// staggered ~800cy so CU store issue is near-continuous, and a store-stall
// on one SIMD overlaps integrate on the others. All chunk-boundary cache
// lines stay within one block (one XCD L2) -- R6 lesson.

#define ROW_F  124    // LDS row stride in floats (31 float4, odd -> bank spread)

__device__ __forceinline__ void rk4_step(float beta, float gamma,
                                         float& S, float& I, float& R)
{
    const float dt = 100.0f / 199.0f;
    const float h2 = 0.5f * dt;
    const float h6 = dt / 6.0f;
    float bSI1 = beta * S * I;
    float gI1  = gamma * I;
    float k1S = -bSI1, k1I = bSI1 - gI1, k1R = gI1;
    float S2 = __builtin_fmaf(h2, k1S, S);
    float I2 = __builtin_fmaf(h2, k1I, I);
    float bSI2 = beta * S2 * I2;
    float gI2  = gamma * I2;
    float k2S = -bSI2, k2I = bSI2 - gI2, k2R = gI2;
    float S3 = __builtin_fmaf(h2, k2S, S);
    float I3 = __builtin_fmaf(h2, k2I, I);
    float bSI3 = beta * S3 * I3;
    float gI3  = gamma * I3;
    float k3S = -bSI3, k3I = bSI3 - gI3, k3R = gI3;
    float S4 = __builtin_fmaf(dt, k3S, S);
    float I4 = __builtin_fmaf(dt, k3I, I);
    float bSI4 = beta * S4 * I4;
    float gI4  = gamma * I4;
    float k4S = -bSI4, k4I = bSI4 - gI4, k4R = gI4;
    S = __builtin_fmaf(h6, k1S + 2.0f * (k2S + k3S) + k4S, S);
    I = __builtin_fmaf(h6, k1I + 2.0f * (k2I + k3I) + k4I, I);
    R = __builtin_fmaf(h6, k1R + 2.0f * (k2R + k3R) + k4R, R);
}

// Integrate C points (C % 4 == 0) into this thread's LDS row.
// If FIRST, point 0 is the current state (no leading step).
template <int C, bool FIRST>
__device__ __forceinline__ void integrate_chunk(
    float beta, float gamma, float& S, float& I, float& R, float* lrowf)
{
    float4* lrow = reinterpret_cast<float4*>(lrowf);
    #pragma unroll
    for (int g = 0; g < C / 4; ++g) {
        float4 va, vb, vc;
        if (FIRST && g == 0) { va.x = S; va.y = I; va.z = R; }
        else { rk4_step(beta, gamma, S, I, R); va.x = S; va.y = I; va.z = R; }
        rk4_step(beta, gamma, S, I, R); va.w = S; vb.x = I; vb.y = R;
        rk4_step(beta, gamma, S, I, R); vb.z = S; vb.w = I; vc.x = R;
        rk4_step(beta, gamma, S, I, R); vc.y = S; vc.z = I; vc.w = R;
        lrow[g * 3 + 0] = va;
        lrow[g * 3 + 1] = vb;
        lrow[g * 3 + 2] = vc;
    }
}

// Coalesced flush of a C-point chunk: 64 rows x (3C/4) float4.
// Compile-time NF4 -> division becomes magic-multiply.
template <int C>
__device__ __forceinline__ void flush_chunk(
    const float* lbuf, float4* gout, int coff, int t)
{
    constexpr int NF4 = 3 * C / 4;
    #pragma unroll
    for (int it = 0; it < NF4; ++it) {
        int f = it * 64 + t;
        int r = f / NF4;
        int q = f - r * NF4;
        float4 v = *reinterpret_cast<const float4*>(&lbuf[r * ROW_F + q * 4]);
        gout[(size_t)r * 150 + coff + q] = v;
    }
}

// Schedule: F + 4x40 + (40-F) = 200 points.
template <int F>
__device__ __forceinline__ void run_sched(
    float beta, float gamma, float S, float I, float R,
    float* lbuf, float4* gout, int t)
{
    float* lrow = &lbuf[t * ROW_F];
    int coff = 0;
    integrate_chunk<F, true>(beta, gamma, S, I, R, lrow);
    flush_chunk<F>(lbuf, gout, coff, t);
    coff += 3 * F / 4;
    #pragma unroll 1
    for (int m = 0; m < 4; ++m) {
        integrate_chunk<40, false>(beta, gamma, S, I, R, lrow);
        flush_chunk<40>(lbuf, gout, coff, t);
        coff += 30;
    }
    if constexpr (F < 40) {
        constexpr int L = 40 - F;
        integrate_chunk<L, false>(beta, gamma, S, I, R, lrow);
        flush_chunk<L>(lbuf, gout, coff, t);
    }
}

__global__ __launch_bounds__(64) void sir_rk4_kernel(
    const float* __restrict__ params, float* __restrict__ out)
{
    const int t  = threadIdx.x;
    const int b0 = blockIdx.x * 64;
    const int w  = (blockIdx.x >> 8) & 3;   // co-resident blocks differ in w

    __shared__ float lbuf[64 * ROW_F];

    const float4 p = reinterpret_cast<const float4*>(params)[b0 + t];
    const float beta = p.x, gamma = p.y;
    float S = p.z, I = p.w;
    float R = 1.0f - S - I;

    float4* gout = reinterpret_cast<float4*>(out) + (size_t)b0 * 150;

    switch (w) {
        case 0:  run_sched<12>(beta, gamma, S, I, R, lbuf, gout, t); break;
        case 1:  run_sched<24>(beta, gamma, S, I, R, lbuf, gout, t); break;
        case 2:  run_sched<36>(beta, gamma, S, I, R, lbuf, gout, t); break;
        default: run_sched<40>(beta, gamma, S, I, R, lbuf, gout, t); break;
    }
}

extern "C" void kernel_launch(void* const* d_in, const int* in_sizes, int n_in,
                              void* d_out, int out_size, void* d_ws, size_t ws_size,
                              hipStream_t stream) {
    const float* params = (const float*)d_in[0];
    float* out = (float*)d_out;
    const int B = in_sizes[0] / 4;           // 65536
    const int grid = B / 64;                 // 1024 blocks
    sir_rk4_kernel<<<grid, 64, 0, stream>>>(params, out);
}

// Round 8
// 39.312 us; speedup vs baseline: 1.6977x; 1.6977x over previous
//
#include <hip/hip_runtime.h>

// SIR RK4, B=65536, 200 points, out (B,200,3) f32 = 157.3 MB.
// Round 8: 2 waves/SIMD via trajectory time-split. R7 counters showed write
// traffic is ideal (160 MB) -> plateau is lack of intra-SIMD overlap at
// 1 wave/SIMD (store-drain 24us + LDS 6us + VALU 5us serialize = 36us).
// 2048 single-wave blocks: block b = (group b&1023, half b>>10). Pair
// (b, b+1024) is same XCD (1024%8==0) so the 1200B half-boundary line merges
// in one L2. Half 1: 100 warmup steps (unstored). Chunks of 20 points,
// LDS 17.4KB -> 8 blocks/CU = 2 waves/SIMD.

#define ROW_F 68     // 20 pts * 3 = 60 floats + 8 pad; stride 17 float4 (odd)

__device__ __forceinline__ void rk4_step(float beta, float gamma,
                                         float& S, float& I, float& R)
{
    const float dt = 100.0f / 199.0f;
    const float h2 = 0.5f * dt;
    const float h6 = dt / 6.0f;
    float bSI1 = beta * S * I;
    float gI1  = gamma * I;
    float k1S = -bSI1, k1I = bSI1 - gI1, k1R = gI1;
    float S2 = __builtin_fmaf(h2, k1S, S);
    float I2 = __builtin_fmaf(h2, k1I, I);
    float bSI2 = beta * S2 * I2;
    float gI2  = gamma * I2;
    float k2S = -bSI2, k2I = bSI2 - gI2, k2R = gI2;
    float S3 = __builtin_fmaf(h2, k2S, S);
    float I3 = __builtin_fmaf(h2, k2I, I);
    float bSI3 = beta * S3 * I3;
    float gI3  = gamma * I3;
    float k3S = -bSI3, k3I = bSI3 - gI3, k3R = gI3;
    float S4 = __builtin_fmaf(dt, k3S, S);
    float I4 = __builtin_fmaf(dt, k3I, I);
    float bSI4 = beta * S4 * I4;
    float gI4  = gamma * I4;
    float k4S = -bSI4, k4I = bSI4 - gI4, k4R = gI4;
    S = __builtin_fmaf(h6, k1S + 2.0f * (k2S + k3S) + k4S, S);
    I = __builtin_fmaf(h6, k1I + 2.0f * (k2I + k3I) + k4I, I);
    R = __builtin_fmaf(h6, k1R + 2.0f * (k2R + k3R) + k4R, R);
}

// Integrate a 20-point chunk into this thread's LDS row.
// FIRST: point 0 of the chunk is the current state (no leading step).
template <bool FIRST>
__device__ __forceinline__ void integrate_chunk20(
    float beta, float gamma, float& S, float& I, float& R, float* lrowf)
{
    float4* lrow = reinterpret_cast<float4*>(lrowf);
    #pragma unroll
    for (int g = 0; g < 5; ++g) {
        float4 va, vb, vc;
        if (FIRST && g == 0) { va.x = S; va.y = I; va.z = R; }
        else { rk4_step(beta, gamma, S, I, R); va.x = S; va.y = I; va.z = R; }
        rk4_step(beta, gamma, S, I, R); va.w = S; vb.x = I; vb.y = R;
        rk4_step(beta, gamma, S, I, R); vb.z = S; vb.w = I; vc.x = R;
        rk4_step(beta, gamma, S, I, R); vc.y = S; vc.z = I; vc.w = R;
        lrow[g * 3 + 0] = va;
        lrow[g * 3 + 1] = vb;
        lrow[g * 3 + 2] = vc;
    }
}

__global__ __launch_bounds__(64) void sir_rk4_kernel(
    const float* __restrict__ params, float* __restrict__ out)
{
    const int t    = threadIdx.x;
    const int bid  = blockIdx.x;
    const int half = bid >> 10;          // 0: points 0..99, 1: points 100..199
    const int grp  = bid & 1023;
    const int b0   = grp * 64;

    __shared__ float lbuf[64 * ROW_F];

    const float4 p = reinterpret_cast<const float4*>(params)[b0 + t];
    const float beta = p.x, gamma = p.y;
    float S = p.z, I = p.w;
    float R = 1.0f - S - I;

    if (half) {
        // warm up to the state at point 100 (after step 100), unstored
        #pragma unroll 4
        for (int j = 0; j < 100; ++j) rk4_step(beta, gamma, S, I, R);
    }

    float* lrow = &lbuf[t * ROW_F];
    // 600 floats per output row = 150 float4; this half starts at float4 75*half
    float4* gout = reinterpret_cast<float4*>(out) + (size_t)b0 * 150 + half * 75;

    // 5 chunks x 20 points; barrier-free single-wave block
    integrate_chunk20<true>(beta, gamma, S, I, R, lrow);
    #pragma unroll
    for (int it = 0; it < 15; ++it) {
        int f = it * 64 + t;
        int r = f / 15;
        int q = f - r * 15;
        float4 v = *reinterpret_cast<const float4*>(&lbuf[r * ROW_F + q * 4]);
        gout[(size_t)r * 150 + q] = v;
    }
    #pragma unroll 1
    for (int c = 1; c < 5; ++c) {
        integrate_chunk20<false>(beta, gamma, S, I, R, lrow);
        const int coff = c * 15;
        #pragma unroll
        for (int it = 0; it < 15; ++it) {
            int f = it * 64 + t;
            int r = f / 15;
            int q = f - r * 15;
            float4 v = *reinterpret_cast<const float4*>(&lbuf[r * ROW_F + q * 4]);
            gout[(size_t)r * 150 + coff + q] = v;
        }
    }
}

extern "C" void kernel_launch(void* const* d_in, const int* in_sizes, int n_in,
                              void* d_out, int out_size, void* d_ws, size_t ws_size,
                              hipStream_t stream) {
    const float* params = (const float*)d_in[0];
    float* out = (float*)d_out;
    const int B = in_sizes[0] / 4;           // 65536
    const int grid = (B / 64) * 2;           // 2048 blocks (half-trajectory each)
    sir_rk4_kernel<<<grid, 64, 0, stream>>>(params, out);
}